// Round 4
// baseline (840.578 us; speedup 1.0000x reference)
//
#include <hip/hip_runtime.h>
#include <hip/hip_bf16.h>

typedef __attribute__((ext_vector_type(8))) short short8;
typedef __attribute__((ext_vector_type(4))) float floatx4;
typedef unsigned short u16;

#define T_SZ 609
#define K1V  4872   // valid K of flattened LSTM output (609*8)
#define K1P  4896   // padded to multiple of 32

static __device__ __forceinline__ u16 f2bf(float f) {
    union { float f; unsigned u; } a; a.f = f;
    unsigned r = a.u + 0x7FFF + ((a.u >> 16) & 1);   // round-to-nearest-even
    return (u16)(r >> 16);
}

// async global->LDS, 16B per lane; LDS dest = wave-uniform base + lane*16
static __device__ __forceinline__ void gload_lds16(const u16* g, u16* l) {
    __builtin_amdgcn_global_load_lds(
        (const __attribute__((address_space(1))) void*)g,
        (__attribute__((address_space(3))) void*)l, 16, 0, 0);
}

// ==================== fp32 -> bf16 conversion (plain) ====================
__global__ __launch_bounds__(256) void cvt_kernel(const float* __restrict__ s,
                                                  u16* __restrict__ d, int n) {
    int i = (blockIdx.x * 256 + threadIdx.x) * 8;
    if (i < n) {
        float4 a = *(const float4*)(s + i);
        float4 b = *(const float4*)(s + i + 4);
        u16 o[8] = { f2bf(a.x), f2bf(a.y), f2bf(a.z), f2bf(a.w),
                     f2bf(b.x), f2bf(b.y), f2bf(b.z), f2bf(b.w) };
        *(uint4*)(d + i) = *(const uint4*)o;
    }
}

// ============== fp32 -> bf16 with row/col zero padding ==============
__global__ __launch_bounds__(256) void cvt_pad_kernel(const float* __restrict__ s,
                                                      u16* __restrict__ d,
                                                      int R, int K, int Kp) {
    int chunk = blockIdx.x * 256 + threadIdx.x;
    int cpr = Kp >> 3;
    int r = chunk / cpr;
    int c = (chunk - r * cpr) << 3;
    u16 o[8] = {0, 0, 0, 0, 0, 0, 0, 0};
    if (r < R && c < K) {
        const float* p = s + (size_t)r * K + c;
        float4 a = *(const float4*)p;
        float4 b = *(const float4*)(p + 4);
        o[0] = f2bf(a.x); o[1] = f2bf(a.y); o[2] = f2bf(a.z); o[3] = f2bf(a.w);
        o[4] = f2bf(b.x); o[5] = f2bf(b.y); o[6] = f2bf(b.z); o[7] = f2bf(b.w);
    }
    *(uint4*)&d[(size_t)r * Kp + c] = *(const uint4*)o;
}

// ============================ LSTM (3 fused layers, fp32) ============================
// One WAVE per batch row: lane = half*32 + gate (gate 0..31; i/f/g/o x 8 units).
// Each lane computes a half-length dot (k-split), reduced with shfl_xor(32).
// Gate gather via xor algebra: p=v*xor16(v)=i*g, xor8(v)=f, xor24(v)=o (valid in
// gate-lanes gi<8 of each half; other lanes compute bounded garbage, never read).
// Broadcast: each lane needs only its k-range of h -> 4 shfls per h vector.
// 4 rows/block, 512 blocks -> 2048 waves = 2 waves/SIMD.
// Layers software-pipelined: iteration t runs L3[t-2], L2[t-1], L1[t].
__global__ __launch_bounds__(256) void lstm3_kernel(
    const float* __restrict__ x,
    const float* __restrict__ Wih1, const float* __restrict__ Whh1,
    const float* __restrict__ bih1, const float* __restrict__ bhh1,
    const float* __restrict__ Wih2, const float* __restrict__ Whh2,
    const float* __restrict__ bih2, const float* __restrict__ bhh2,
    const float* __restrict__ Wih3, const float* __restrict__ Whh3,
    const float* __restrict__ bih3, const float* __restrict__ bhh3,
    u16* __restrict__ A1)
{
    __shared__ float xs[4 * T_SZ * 5];   // 48,720 B
    const int tid = threadIdx.x;
    const int b0  = blockIdx.x * 4;

    const float* xg = x + (size_t)b0 * (T_SZ * 5);
    for (int i = tid; i < 4 * T_SZ * 5; i += 256) xs[i] = xg[i];

    // zero the K padding columns of A1 (ws is poisoned each launch)
    if (tid < 96) {
        int r = tid / 24, c = tid - r * 24;
        A1[(size_t)(b0 + r) * K1P + K1V + c] = 0;
    }

    const int lane = tid & 63;
    const int gi   = lane & 31;        // gate index (i:0-7, f:8-15, g:16-23, o:24-31)
    const int half = lane >> 5;        // k-split half
    const int koff = half * 4;         // this lane's h k-range start
    const int gt   = gi >> 3;
    const int rw   = tid >> 6;         // wave = local row
    const int bb   = b0 + rw;
    const int srcb = (lane & 32) + koff;  // broadcast source base (gate-lanes of own half)

    // per-lane partial weight rows (fp32, registers)
    float wi1[5], wh1[4], wi2[4], wh2[4], wi3[4], wh3[4];
#pragma unroll
    for (int k = 0; k < 5; ++k) wi1[k] = half ? 0.f : Wih1[gi * 5 + k];
#pragma unroll
    for (int k = 0; k < 4; ++k) {
        wh1[k] = Whh1[gi * 8 + koff + k];
        wi2[k] = Wih2[gi * 8 + koff + k];
        wh2[k] = Whh2[gi * 8 + koff + k];
        wi3[k] = Wih3[gi * 8 + koff + k];
        wh3[k] = Whh3[gi * 8 + koff + k];
    }
    const float bs1 = half ? 0.f : bih1[gi] + bhh1[gi];
    const float bs2 = half ? 0.f : bih2[gi] + bhh2[gi];
    const float bs3 = half ? 0.f : bih3[gi] + bhh3[gi];

    // branchless activation: sigmoid for i/f/o, tanh (=2*sigm(2x)-1) for g
    const float am = (gt == 2) ? -2.f : -1.f;
    const float aa = (gt == 2) ?  2.f :  1.f;
    const float ab = (gt == 2) ? -1.f :  0.f;

    __syncthreads();

    float c1 = 0.f, c2 = 0.f, c3 = 0.f;
    float hh1[4], hh2[4], hh3[4];      // this lane's k-range of each layer's h
#pragma unroll
    for (int k = 0; k < 4; ++k) { hh1[k] = 0.f; hh2[k] = 0.f; hh3[k] = 0.f; }

    const float* xr = &xs[rw * (T_SZ * 5)];
    u16* outp = A1 + (size_t)bb * K1P;

    // partial-dot in, h out (valid in gate-lanes gi<8 of each half)
    auto lstep = [&](float a, float& c) -> float {
        float v = a + __shfl_xor(a, 32, 64);              // k-reduce: full gate preact
        float e = __expf(am * v);
        float act = __builtin_fmaf(aa, __fdividef(1.f, 1.f + e), ab);
        float p  = act * __shfl_xor(act, 16, 64);         // i*g in gate-lanes
        float f_ = __shfl_xor(act, 8, 64);                // f in gate-lanes
        float o_ = __shfl_xor(act, 24, 64);               // o in gate-lanes
        c = __builtin_fmaf(f_, c, p);
        float ec = __expf(-2.f * __builtin_fabsf(c));
        float th = (1.f - ec) * __fdividef(1.f, 1.f + ec);
        return o_ * __builtin_copysignf(th, c);
    };

    auto step1 = [&](int t) {
        float a = bs1;
#pragma unroll
        for (int k = 0; k < 5; ++k) a = __builtin_fmaf(wi1[k], xr[t * 5 + k], a);
#pragma unroll
        for (int k = 0; k < 4; ++k) a = __builtin_fmaf(wh1[k], hh1[k], a);
        float h = lstep(a, c1);
#pragma unroll
        for (int k = 0; k < 4; ++k) hh1[k] = __shfl(h, srcb + k, 64);
    };
    auto step2 = [&]() {
        float a = bs2;
#pragma unroll
        for (int k = 0; k < 4; ++k) a = __builtin_fmaf(wi2[k], hh1[k], a);
#pragma unroll
        for (int k = 0; k < 4; ++k) a = __builtin_fmaf(wh2[k], hh2[k], a);
        float h = lstep(a, c2);
#pragma unroll
        for (int k = 0; k < 4; ++k) hh2[k] = __shfl(h, srcb + k, 64);
    };
    auto step3 = [&](int t) {
        float a = bs3;
#pragma unroll
        for (int k = 0; k < 4; ++k) a = __builtin_fmaf(wi3[k], hh2[k], a);
#pragma unroll
        for (int k = 0; k < 4; ++k) a = __builtin_fmaf(wh3[k], hh3[k], a);
        float h = lstep(a, c3);
#pragma unroll
        for (int k = 0; k < 4; ++k) hh3[k] = __shfl(h, srcb + k, 64);
        if (lane < 8) outp[t * 8 + lane] = f2bf(h);
    };

    // pipeline prologue
    step1(0);
    step2(); step1(1);
    // main loop: three independent chains per iteration
    for (int t = 2; t < T_SZ; ++t) {
        step3(t - 2);
        step2();
        step1(t);
    }
    // drain
    step3(T_SZ - 2);
    step2();
    step3(T_SZ - 1);
}

// ============================ bf16 NT GEMM + bias + (ReLU) ============================
// C[m][n] = act( sum_k A[m][k]*B[n][k] + bias[n] ). 16x16x32 bf16 MFMA, BK=32,
// m97-style async staging: global_load_lds dwordx4, unpadded LDS (row = 32 u16).
template<int BM, int BN, bool RELU, bool NGUARD, bool OUTF32>
__global__ __launch_bounds__(256) void gemm_bt(
    const u16* __restrict__ A, int lda,
    const u16* __restrict__ B, int ldb,
    const float* __restrict__ bias,
    void* __restrict__ Cv, int ldc, int N, int K)
{
    constexpr int WM = BM / 2, WN = BN / 2;
    constexpr int TM = WM / 16, TN = WN / 16;
    __shared__ u16 As[BM * 32];
    __shared__ u16 Bs[BN * 32];

    const int tid = threadIdx.x;
    const int bm  = blockIdx.y * BM;
    const int bn  = blockIdx.x * BN;
    const int l   = tid & 63, w = tid >> 6;
    const int wr  = w >> 1, wc = w & 1;
    const int lr  = l & 15, q = l >> 4;
    const int lrow = l >> 2;            // staging: lane -> row within 16-row group
    const int lcol = (l & 3) << 3;      // staging: lane -> 8-elem chunk

    floatx4 acc[TM][TN];
#pragma unroll
    for (int i = 0; i < TM; ++i)
#pragma unroll
        for (int j = 0; j < TN; ++j) acc[i][j] = (floatx4){0.f, 0.f, 0.f, 0.f};

    const u16* Ab = A + (size_t)bm * lda;
    const u16* Bb = B + (size_t)bn * ldb;

    for (int k0 = 0; k0 < K; k0 += 32) {
#pragma unroll
        for (int i = 0; i < BM / 64; ++i) {
            int r0 = w * (BM / 4) + i * 16;
            gload_lds16(Ab + (size_t)(r0 + lrow) * lda + k0 + lcol, &As[r0 * 32]);
        }
#pragma unroll
        for (int i = 0; i < BN / 64; ++i) {
            int r0 = w * (BN / 4) + i * 16;
            gload_lds16(Bb + (size_t)(r0 + lrow) * ldb + k0 + lcol, &Bs[r0 * 32]);
        }
        __syncthreads();

        short8 fa[TM], fb[TN];
#pragma unroll
        for (int i = 0; i < TM; ++i)
            fa[i] = *(const short8*)&As[(wr * WM + i * 16 + lr) * 32 + q * 8];
#pragma unroll
        for (int j = 0; j < TN; ++j)
            fb[j] = *(const short8*)&Bs[(wc * WN + j * 16 + lr) * 32 + q * 8];
#pragma unroll
        for (int i = 0; i < TM; ++i)
#pragma unroll
            for (int j = 0; j < TN; ++j)
                acc[i][j] = __builtin_amdgcn_mfma_f32_16x16x32_bf16(fa[i], fb[j], acc[i][j], 0, 0, 0);
        __syncthreads();
    }

    // epilogue: C/D layout col = lane&15, row = (lane>>4)*4 + reg  [m89/m91]
#pragma unroll
    for (int j = 0; j < TN; ++j) {
        int n = bn + wc * WN + j * 16 + lr;
        bool nok = (!NGUARD) || (n < N);
        float bv = nok ? bias[n] : 0.f;
#pragma unroll
        for (int i = 0; i < TM; ++i) {
            int m0r = bm + wr * WM + i * 16 + q * 4;
#pragma unroll
            for (int r = 0; r < 4; ++r) {
                float vv = acc[i][j][r] + bv;
                if (RELU) vv = fmaxf(vv, 0.f);
                if (nok) {
                    size_t idx = (size_t)(m0r + r) * ldc + n;
                    if (OUTF32) ((float*)Cv)[idx] = vv;
                    else        ((u16*)Cv)[idx] = f2bf(vv);
                }
            }
        }
    }
}

// ============================ launch ============================
extern "C" void kernel_launch(void* const* d_in, const int* in_sizes, int n_in,
                              void* d_out, int out_size, void* d_ws, size_t ws_size,
                              hipStream_t stream)
{
    const float* x    = (const float*)d_in[0];
    const float* Wih1 = (const float*)d_in[1];
    const float* Whh1 = (const float*)d_in[2];
    const float* bih1 = (const float*)d_in[3];
    const float* bhh1 = (const float*)d_in[4];
    const float* Wih2 = (const float*)d_in[5];
    const float* Whh2 = (const float*)d_in[6];
    const float* bih2 = (const float*)d_in[7];
    const float* bhh2 = (const float*)d_in[8];
    const float* Wih3 = (const float*)d_in[9];
    const float* Whh3 = (const float*)d_in[10];
    const float* bih3 = (const float*)d_in[11];
    const float* bhh3 = (const float*)d_in[12];
    const float* W1 = (const float*)d_in[13];
    const float* b1 = (const float*)d_in[14];
    const float* W2 = (const float*)d_in[15];
    const float* b2 = (const float*)d_in[16];
    const float* W3 = (const float*)d_in[17];
    const float* b3 = (const float*)d_in[18];

    // ws layout (bf16 elems): A1[2048][4896], A2[2048][4096], A3[2048][1024],
    // W1b[4096][4896] (K-padded), W2b[1024][4096], W3b[640][1024] (row-padded). ~91 MB.
    u16* A1  = (u16*)d_ws;
    u16* A2  = A1  + (size_t)2048 * K1P;
    u16* A3  = A2  + (size_t)2048 * 4096;
    u16* W1b = A3  + (size_t)2048 * 1024;
    u16* W2b = W1b + (size_t)4096 * K1P;
    u16* W3b = W2b + (size_t)1024 * 4096;

    // weight conversions fp32 -> bf16 (zero-padded where needed)
    cvt_pad_kernel<<<9792, 256, 0, stream>>>(W1, W1b, 4096, K1V, K1P);
    cvt_kernel<<<2048, 256, 0, stream>>>(W2, W2b, 1024 * 4096);
    cvt_pad_kernel<<<320, 256, 0, stream>>>(W3, W3b, T_SZ, 1024, 1024);

    lstm3_kernel<<<512, 256, 0, stream>>>(x, Wih1, Whh1, bih1, bhh1,
                                          Wih2, Whh2, bih2, bhh2,
                                          Wih3, Whh3, bih3, bhh3, A1);

    // L1: [2048,4896] x W1b[4096,4896] -> relu -> A2 [2048,4096]  (bf16 out)
    gemm_bt<128, 128, true, false, false><<<dim3(32, 16), 256, 0, stream>>>(
        A1, K1P, W1b, K1P, b1, A2, 4096, 4096, K1P);

    // L2: [2048,4096] x W2b[1024,4096] -> relu -> A3 [2048,1024]  (bf16 out)
    gemm_bt<64, 128, true, false, false><<<dim3(8, 32), 256, 0, stream>>>(
        A2, 4096, W2b, 4096, b2, A3, 1024, 1024, 4096);

    // L3: [2048,1024] x W3b[640,1024] -> d_out [2048,609]  (fp32 out, store N-guard)
    gemm_bt<64, 128, false, true, true><<<dim3(5, 32), 256, 0, stream>>>(
        A3, 1024, W3b, 1024, b3, d_out, T_SZ, T_SZ, 1024);
}

// Round 5
// 699.626 us; speedup vs baseline: 1.2015x; 1.2015x over previous
//
#include <hip/hip_runtime.h>
#include <hip/hip_bf16.h>

typedef __attribute__((ext_vector_type(8))) short short8;
typedef __attribute__((ext_vector_type(4))) float floatx4;
typedef unsigned short u16;

#define T_SZ 609
#define K1V  4872   // valid K of flattened LSTM output (609*8)
#define K1P  4896   // padded to multiple of 32
#define RD   4      // LDS ring depth (slots)

static __device__ __forceinline__ u16 f2bf(float f) {
    union { float f; unsigned u; } a; a.f = f;
    unsigned r = a.u + 0x7FFF + ((a.u >> 16) & 1);   // round-to-nearest-even
    return (u16)(r >> 16);
}

// async global->LDS, 16B per lane; LDS dest = wave-uniform base + lane*16
static __device__ __forceinline__ void gload_lds16(const u16* g, u16* l) {
    __builtin_amdgcn_global_load_lds(
        (const __attribute__((address_space(1))) void*)g,
        (__attribute__((address_space(3))) void*)l, 16, 0, 0);
}

#define WG_LOAD(p)     __hip_atomic_load((p), __ATOMIC_ACQUIRE, __HIP_MEMORY_SCOPE_WORKGROUP)
#define WG_STORE(p, v) __hip_atomic_store((p), (v), __ATOMIC_RELEASE, __HIP_MEMORY_SCOPE_WORKGROUP)

// ==================== fp32 -> bf16 conversion (plain) ====================
__global__ __launch_bounds__(256) void cvt_kernel(const float* __restrict__ s,
                                                  u16* __restrict__ d, int n) {
    int i = (blockIdx.x * 256 + threadIdx.x) * 8;
    if (i < n) {
        float4 a = *(const float4*)(s + i);
        float4 b = *(const float4*)(s + i + 4);
        u16 o[8] = { f2bf(a.x), f2bf(a.y), f2bf(a.z), f2bf(a.w),
                     f2bf(b.x), f2bf(b.y), f2bf(b.z), f2bf(b.w) };
        *(uint4*)(d + i) = *(const uint4*)o;
    }
}

// ============== fp32 -> bf16 with row/col zero padding ==============
__global__ __launch_bounds__(256) void cvt_pad_kernel(const float* __restrict__ s,
                                                      u16* __restrict__ d,
                                                      int R, int K, int Kp) {
    int chunk = blockIdx.x * 256 + threadIdx.x;
    int cpr = Kp >> 3;
    int r = chunk / cpr;
    int c = (chunk - r * cpr) << 3;
    u16 o[8] = {0, 0, 0, 0, 0, 0, 0, 0};
    if (r < R && c < K) {
        const float* p = s + (size_t)r * K + c;
        float4 a = *(const float4*)p;
        float4 b = *(const float4*)(p + 4);
        o[0] = f2bf(a.x); o[1] = f2bf(a.y); o[2] = f2bf(a.z); o[3] = f2bf(a.w);
        o[4] = f2bf(b.x); o[5] = f2bf(b.y); o[6] = f2bf(b.z); o[7] = f2bf(b.w);
    }
    *(uint4*)&d[(size_t)r * Kp + c] = *(const uint4*)o;
}

// ============================ LSTM (wave-specialized pipeline) ============================
// Block = 2 batch rows, 3 waves: wave w runs LSTM layer w for both rows over all t.
// Lane layout within a wave (R3's): lane = rowhalf*32 + gate (i:0-7,f:8-15,g:16-23,o:24-31).
// h handoff L1->L2->L3 via depth-RD LDS rings with acquire/release flag counters
// (workgroup scope; all 3 waves co-resident by definition -> no deadlock).
// Each wave's own recurrent h comes from reading back its own ring slot (2x ds_read_b128)
// instead of 8 shfl broadcasts. Gather of i/f/g/o stays 4 indexed shfls (R3, verified).
__global__ __launch_bounds__(192) void lstm3_kernel(
    const float* __restrict__ x,
    const float* __restrict__ Wih1, const float* __restrict__ Whh1,
    const float* __restrict__ bih1, const float* __restrict__ bhh1,
    const float* __restrict__ Wih2, const float* __restrict__ Whh2,
    const float* __restrict__ bih2, const float* __restrict__ bhh2,
    const float* __restrict__ Wih3, const float* __restrict__ Whh3,
    const float* __restrict__ bih3, const float* __restrict__ bhh3,
    u16* __restrict__ A1)
{
    __shared__ __align__(16) float xs[2 * T_SZ * 5];          // 24,360 B
    __shared__ __align__(16) float r1[RD * 16], r2[RD * 16], r3[RD * 16];
    __shared__ int p1, p2, c2, c3;

    const int tid = threadIdx.x;
    const int b0  = blockIdx.x * 2;

    const float* xg = x + (size_t)b0 * (T_SZ * 5);
    for (int i = tid; i < 2 * T_SZ * 5; i += 192) xs[i] = xg[i];
    if (tid == 0) { p1 = 0; p2 = 0; c2 = 0; c3 = 0; }
    // zero the K padding columns of A1 (ws is poisoned each launch)
    if (tid < 48) {
        int r = tid / 24, c = tid - r * 24;
        A1[(size_t)(b0 + r) * K1P + K1V + c] = 0;
    }
    __syncthreads();

    const int lane = tid & 63, wid = tid >> 6;
    const int gi   = lane & 31;        // gate index
    const int rh   = lane >> 5;        // row half (0/1)
    const int jj   = gi & 7;           // hidden unit this lane owns
    const int gt   = gi >> 3;
    const int base = lane & 32;

    // branchless activation: sigmoid for i/f/o, tanh (=2*sigm(2x)-1) for g
    const float am = (gt == 2) ? -2.f : -1.f;
    const float aa = (gt == 2) ?  2.f :  1.f;
    const float ab = (gt == 2) ? -1.f :  0.f;

    // gate preact in, h out (valid in all lanes for own unit jj)
    auto lstep = [&](float a, float& c) -> float {
        float e = __expf(am * a);
        float v = __builtin_fmaf(aa, __fdividef(1.f, 1.f + e), ab);
        float vi = __shfl(v, base + jj,      64);
        float vf = __shfl(v, base + 8 + jj,  64);
        float vg = __shfl(v, base + 16 + jj, 64);
        float vo = __shfl(v, base + 24 + jj, 64);
        c = __builtin_fmaf(vf, c, vi * vg);
        float ec = __expf(-2.f * __builtin_fabsf(c));
        float th = (1.f - ec) * __fdividef(1.f, 1.f + ec);
        return vo * __builtin_copysignf(th, c);
    };

    // dot of 8 recurrent/input terms from a 16B-aligned LDS slot
    auto dot8 = [&](const float* hp, const float* w, float& a, float& b) {
        float4 h0 = *(const float4*)hp;
        float4 h1 = *(const float4*)(hp + 4);
        a = __builtin_fmaf(w[0], h0.x, a); b = __builtin_fmaf(w[1], h0.y, b);
        a = __builtin_fmaf(w[2], h0.z, a); b = __builtin_fmaf(w[3], h0.w, b);
        a = __builtin_fmaf(w[4], h1.x, a); b = __builtin_fmaf(w[5], h1.y, b);
        a = __builtin_fmaf(w[6], h1.z, a); b = __builtin_fmaf(w[7], h1.w, b);
    };

    if (wid == 0) {
        // ---------------- L1 wave ----------------
        float wi[5], wh[8];
#pragma unroll
        for (int k = 0; k < 5; ++k) wi[k] = Wih1[gi * 5 + k];
#pragma unroll
        for (int k = 0; k < 8; ++k) wh[k] = Whh1[gi * 8 + k];
        const float bs = bih1[gi] + bhh1[gi];
        const float* xr = &xs[rh * (T_SZ * 5)];
        float cst = 0.f;
        for (int t = 0; t < T_SZ; ++t) {
            float a = bs, b = 0.f;
#pragma unroll
            for (int k = 0; k < 5; ++k) a = __builtin_fmaf(wi[k], xr[t * 5 + k], a);
            if (t > 0) dot8(&r1[((t - 1) & (RD - 1)) * 16 + rh * 8], wh, a, b);
            float h = lstep(a + b, cst);
            if (t >= RD) while (WG_LOAD(&c2) < t - (RD - 1)) {}
            if (gi < 8) r1[(t & (RD - 1)) * 16 + rh * 8 + jj] = h;
            if (lane == 0) WG_STORE(&p1, t + 1);
        }
    } else if (wid == 1) {
        // ---------------- L2 wave ----------------
        float wi[8], wh[8];
#pragma unroll
        for (int k = 0; k < 8; ++k) { wi[k] = Wih2[gi * 8 + k]; wh[k] = Whh2[gi * 8 + k]; }
        const float bs = bih2[gi] + bhh2[gi];
        float cst = 0.f;
        for (int t = 0; t < T_SZ; ++t) {
            while (WG_LOAD(&p1) < t + 1) {}
            float a = bs, b = 0.f;
            dot8(&r1[(t & (RD - 1)) * 16 + rh * 8], wi, a, b);
            if (lane == 0) WG_STORE(&c2, t + 1);     // release: reads above are drained
            if (t > 0) dot8(&r2[((t - 1) & (RD - 1)) * 16 + rh * 8], wh, a, b);
            float h = lstep(a + b, cst);
            if (t >= RD) while (WG_LOAD(&c3) < t - (RD - 1)) {}
            if (gi < 8) r2[(t & (RD - 1)) * 16 + rh * 8 + jj] = h;
            if (lane == 0) WG_STORE(&p2, t + 1);
        }
    } else {
        // ---------------- L3 wave ----------------
        float wi[8], wh[8];
#pragma unroll
        for (int k = 0; k < 8; ++k) { wi[k] = Wih3[gi * 8 + k]; wh[k] = Whh3[gi * 8 + k]; }
        const float bs = bih3[gi] + bhh3[gi];
        float cst = 0.f;
        u16* outp = A1 + (size_t)(b0 + rh) * K1P;
        for (int t = 0; t < T_SZ; ++t) {
            while (WG_LOAD(&p2) < t + 1) {}
            float a = bs, b = 0.f;
            dot8(&r2[(t & (RD - 1)) * 16 + rh * 8], wi, a, b);
            if (lane == 0) WG_STORE(&c3, t + 1);
            if (t > 0) dot8(&r3[((t - 1) & (RD - 1)) * 16 + rh * 8], wh, a, b);
            float h = lstep(a + b, cst);
            if (gi < 8) {
                r3[(t & (RD - 1)) * 16 + rh * 8 + jj] = h;   // private ring (no flags)
                outp[t * 8 + jj] = f2bf(h);
            }
        }
    }
}

// ============================ bf16 NT GEMM + bias + (ReLU) ============================
// C[m][n] = act( sum_k A[m][k]*B[n][k] + bias[n] ). 16x16x32 bf16 MFMA, BK=32,
// m97-style async staging: global_load_lds dwordx4, unpadded LDS (row = 32 u16).
template<int BM, int BN, bool RELU, bool NGUARD, bool OUTF32>
__global__ __launch_bounds__(256) void gemm_bt(
    const u16* __restrict__ A, int lda,
    const u16* __restrict__ B, int ldb,
    const float* __restrict__ bias,
    void* __restrict__ Cv, int ldc, int N, int K)
{
    constexpr int WM = BM / 2, WN = BN / 2;
    constexpr int TM = WM / 16, TN = WN / 16;
    __shared__ u16 As[BM * 32];
    __shared__ u16 Bs[BN * 32];

    const int tid = threadIdx.x;
    const int bm  = blockIdx.y * BM;
    const int bn  = blockIdx.x * BN;
    const int l   = tid & 63, w = tid >> 6;
    const int wr  = w >> 1, wc = w & 1;
    const int lr  = l & 15, q = l >> 4;
    const int lrow = l >> 2;            // staging: lane -> row within 16-row group
    const int lcol = (l & 3) << 3;      // staging: lane -> 8-elem chunk

    floatx4 acc[TM][TN];
#pragma unroll
    for (int i = 0; i < TM; ++i)
#pragma unroll
        for (int j = 0; j < TN; ++j) acc[i][j] = (floatx4){0.f, 0.f, 0.f, 0.f};

    const u16* Ab = A + (size_t)bm * lda;
    const u16* Bb = B + (size_t)bn * ldb;

    for (int k0 = 0; k0 < K; k0 += 32) {
#pragma unroll
        for (int i = 0; i < BM / 64; ++i) {
            int r0 = w * (BM / 4) + i * 16;
            gload_lds16(Ab + (size_t)(r0 + lrow) * lda + k0 + lcol, &As[r0 * 32]);
        }
#pragma unroll
        for (int i = 0; i < BN / 64; ++i) {
            int r0 = w * (BN / 4) + i * 16;
            gload_lds16(Bb + (size_t)(r0 + lrow) * ldb + k0 + lcol, &Bs[r0 * 32]);
        }
        __syncthreads();

        short8 fa[TM], fb[TN];
#pragma unroll
        for (int i = 0; i < TM; ++i)
            fa[i] = *(const short8*)&As[(wr * WM + i * 16 + lr) * 32 + q * 8];
#pragma unroll
        for (int j = 0; j < TN; ++j)
            fb[j] = *(const short8*)&Bs[(wc * WN + j * 16 + lr) * 32 + q * 8];
#pragma unroll
        for (int i = 0; i < TM; ++i)
#pragma unroll
            for (int j = 0; j < TN; ++j)
                acc[i][j] = __builtin_amdgcn_mfma_f32_16x16x32_bf16(fa[i], fb[j], acc[i][j], 0, 0, 0);
        __syncthreads();
    }

    // epilogue: C/D layout col = lane&15, row = (lane>>4)*4 + reg  [m89/m91]
#pragma unroll
    for (int j = 0; j < TN; ++j) {
        int n = bn + wc * WN + j * 16 + lr;
        bool nok = (!NGUARD) || (n < N);
        float bv = nok ? bias[n] : 0.f;
#pragma unroll
        for (int i = 0; i < TM; ++i) {
            int m0r = bm + wr * WM + i * 16 + q * 4;
#pragma unroll
            for (int r = 0; r < 4; ++r) {
                float vv = acc[i][j][r] + bv;
                if (RELU) vv = fmaxf(vv, 0.f);
                if (nok) {
                    size_t idx = (size_t)(m0r + r) * ldc + n;
                    if (OUTF32) ((float*)Cv)[idx] = vv;
                    else        ((u16*)Cv)[idx] = f2bf(vv);
                }
            }
        }
    }
}

// ============================ launch ============================
extern "C" void kernel_launch(void* const* d_in, const int* in_sizes, int n_in,
                              void* d_out, int out_size, void* d_ws, size_t ws_size,
                              hipStream_t stream)
{
    const float* x    = (const float*)d_in[0];
    const float* Wih1 = (const float*)d_in[1];
    const float* Whh1 = (const float*)d_in[2];
    const float* bih1 = (const float*)d_in[3];
    const float* bhh1 = (const float*)d_in[4];
    const float* Wih2 = (const float*)d_in[5];
    const float* Whh2 = (const float*)d_in[6];
    const float* bih2 = (const float*)d_in[7];
    const float* bhh2 = (const float*)d_in[8];
    const float* Wih3 = (const float*)d_in[9];
    const float* Whh3 = (const float*)d_in[10];
    const float* bih3 = (const float*)d_in[11];
    const float* bhh3 = (const float*)d_in[12];
    const float* W1 = (const float*)d_in[13];
    const float* b1 = (const float*)d_in[14];
    const float* W2 = (const float*)d_in[15];
    const float* b2 = (const float*)d_in[16];
    const float* W3 = (const float*)d_in[17];
    const float* b3 = (const float*)d_in[18];

    // ws layout (bf16 elems): A1[2048][4896], A2[2048][4096], A3[2048][1024],
    // W1b[4096][4896] (K-padded), W2b[1024][4096], W3b[640][1024] (row-padded). ~91 MB.
    u16* A1  = (u16*)d_ws;
    u16* A2  = A1  + (size_t)2048 * K1P;
    u16* A3  = A2  + (size_t)2048 * 4096;
    u16* W1b = A3  + (size_t)2048 * 1024;
    u16* W2b = W1b + (size_t)4096 * K1P;
    u16* W3b = W2b + (size_t)1024 * 4096;

    // weight conversions fp32 -> bf16 (zero-padded where needed)
    cvt_pad_kernel<<<9792, 256, 0, stream>>>(W1, W1b, 4096, K1V, K1P);
    cvt_kernel<<<2048, 256, 0, stream>>>(W2, W2b, 1024 * 4096);
    cvt_pad_kernel<<<320, 256, 0, stream>>>(W3, W3b, T_SZ, 1024, 1024);

    lstm3_kernel<<<1024, 192, 0, stream>>>(x, Wih1, Whh1, bih1, bhh1,
                                           Wih2, Whh2, bih2, bhh2,
                                           Wih3, Whh3, bih3, bhh3, A1);

    // L1: [2048,4896] x W1b[4096,4896] -> relu -> A2 [2048,4096]  (bf16 out)
    gemm_bt<128, 128, true, false, false><<<dim3(32, 16), 256, 0, stream>>>(
        A1, K1P, W1b, K1P, b1, A2, 4096, 4096, K1P);

    // L2: [2048,4096] x W2b[1024,4096] -> relu -> A3 [2048,1024]  (bf16 out)
    gemm_bt<64, 128, true, false, false><<<dim3(8, 32), 256, 0, stream>>>(
        A2, 4096, W2b, 4096, b2, A3, 1024, 1024, 4096);

    // L3: [2048,1024] x W3b[640,1024] -> d_out [2048,609]  (fp32 out, store N-guard)
    gemm_bt<64, 128, false, true, true><<<dim3(5, 32), 256, 0, stream>>>(
        A3, 1024, W3b, 1024, b3, d_out, T_SZ, T_SZ, 1024);
}